// Round 2
// baseline (214.628 us; speedup 1.0000x reference)
//
#include <hip/hip_runtime.h>
#include <math.h>

#define NQ 14
#define NL 4
#define NS (1 << NQ)      // 16384 amplitudes
#define NT 1024           // threads per block
#define APT (NS / NT)     // 16 amps per thread

struct c32 { float x, y; };
__device__ __forceinline__ c32 cmul(c32 a, c32 b) { return {a.x*b.x - a.y*b.y, a.x*b.y + a.y*b.x}; }
__device__ __forceinline__ c32 cadd(c32 a, c32 b) { return {a.x + b.x, a.y + b.y}; }

// LDS = 137 KB -> 1 block/CU regardless of VGPRs. 1024 thr = 16 waves = 4 waves/EU.
// Declare exactly that occupancy so the compiler gets 128 VGPRs (not 64) and
// the c32 v[16]/tmp[16] arrays stay in registers instead of spilling to
// scratch (round-1: 188 MB HBM scratch traffic at VGPR_Count=64).
__global__ __launch_bounds__(NT, 4)
void qc_kernel(const float* __restrict__ x,
               const float* __restrict__ prx,
               const float* __restrict__ pry,
               const float* __restrict__ prz,
               const float* __restrict__ pent,
               float* __restrict__ out)
{
    __shared__ float2 st[NS];            // 128 KB state
    __shared__ float  Um[NL][NQ][8];     // fused RZ*RY*RX 2x2 complex per (layer,qubit)
    __shared__ float  tlo[NL][128];      // entangle phase table, bit positions 0..6
    __shared__ float  thi[NL][64];       // bit positions 7..12
    __shared__ float  encc[NQ], encs[NQ];
    __shared__ float  red[NT/64][NQ];

    const int tid = threadIdx.x;
    const int b   = blockIdx.x;

    // ---------------- precompute (one barrier) ----------------
    if (tid < NL*NQ) {
        int l = tid / NQ, q = tid % NQ;
        float hx = 0.5f*prx[l*NQ+q], hy = 0.5f*pry[l*NQ+q], hz = 0.5f*prz[l*NQ+q];
        float cx = cosf(hx), sx = sinf(hx);
        float cy = cosf(hy), sy = sinf(hy);
        float cz = cosf(hz), sz = sinf(hz);
        // M = Ry*Rx
        c32 m00 = { cy*cx,  sy*sx };
        c32 m01 = {-sy*cx, -cy*sx };
        c32 m10 = { sy*cx, -cy*sx };
        c32 m11 = { cy*cx, -sy*sx };
        // U = Rz*M : row0 *= e^{-i hz}, row1 *= e^{+i hz}
        c32 e0 = {cz, -sz}, e1 = {cz, sz};
        c32 u00 = cmul(e0, m00), u01 = cmul(e0, m01);
        c32 u10 = cmul(e1, m10), u11 = cmul(e1, m11);
        float* U = Um[l][q];
        U[0]=u00.x; U[1]=u00.y; U[2]=u01.x; U[3]=u01.y;
        U[4]=u10.x; U[5]=u10.y; U[6]=u11.x; U[7]=u11.y;
    } else if (tid >= 64 && tid < 64 + NL*192) {
        int t2 = tid - 64;
        int l = t2 / 192, r = t2 % 192;
        if (r < 128) {                       // positions p=0..6, theta index 12-p
            float a = 0.f;
            for (int p = 0; p < 7; ++p) {
                float th = 0.5f * pent[l*(NQ-1) + (12 - p)];
                a += ((r >> p) & 1) ? th : -th;
            }
            tlo[l][r] = a;
        } else {                             // positions p=7..12, theta index 5-p'
            int m = r - 128;
            float a = 0.f;
            for (int p = 0; p < 6; ++p) {
                float th = 0.5f * pent[l*(NQ-1) + (5 - p)];
                a += ((m >> p) & 1) ? th : -th;
            }
            thi[l][m] = a;
        }
    } else if (tid >= 960 && tid < 960 + NQ) {
        int i = tid - 960;
        float th = tanhf(x[b*NQ + i]) * 3.14159265358979323846f;
        encc[i] = cosf(0.5f*th);
        encs[i] = sinf(0.5f*th);
    }
    __syncthreads();

    // ---------------- init: product state from RY encoding ----------------
    // encc/encs read directly from LDS (wave-uniform broadcast, no register copy)
    {
        float prodLow = 1.f;
        #pragma unroll
        for (int p = 0; p < 10; ++p) {       // idx bits 0..9 come from tid; qubit = 13-p
            prodLow *= ((tid >> p) & 1) ? encs[13-p] : encc[13-p];
        }
        #pragma unroll
        for (int j = 0; j < APT; ++j) {      // idx bits 10..13 come from j; qubit = 3..0
            float a = prodLow;
            a *= (j & 1) ? encs[3] : encc[3];
            a *= (j & 2) ? encs[2] : encc[2];
            a *= (j & 4) ? encs[1] : encc[1];
            a *= (j & 8) ? encs[0] : encc[0];
            st[tid + j*NT] = make_float2(a, 0.f);
        }
    }
    __syncthreads();

    for (int l = 0; l < NL; ++l) {
        // ---- five fused 2-qubit rotation passes: qubit pairs (0,1)..(8,9) ----
        #pragma unroll
        for (int g = 0; g < 5; ++g) {
            const int qa = 2*g, qb = 2*g + 1;
            const int pb = 13 - qb;          // 12,10,8,6,4
            const float* Ua = Um[l][qa];
            const float* Ub = Um[l][qb];
            c32 a00={Ua[0],Ua[1]}, a01={Ua[2],Ua[3]}, a10={Ua[4],Ua[5]}, a11={Ua[6],Ua[7]};
            c32 b00={Ub[0],Ub[1]}, b01={Ub[2],Ub[3]}, b10={Ub[4],Ub[5]}, b11={Ub[6],Ub[7]};
            const int sb = 1 << pb;
            const int maskLow = sb - 1;
            #pragma unroll
            for (int m = 0; m < 4; ++m) {
                int t = tid + m*NT;          // tuple index in [0,4096)
                int i00 = ((t & ~maskLow) << 2) | (t & maskLow);
                int i01 = i00 | sb;
                int i10 = i00 | (sb << 1);
                int i11 = i01 | (sb << 1);
                float2 f00 = st[i00], f01 = st[i01], f10 = st[i10], f11 = st[i11];
                c32 v00 = {f00.x,f00.y}, v01 = {f01.x,f01.y}, v10 = {f10.x,f10.y}, v11 = {f11.x,f11.y};
                // apply Ub across qb-bit
                c32 w00 = cadd(cmul(b00,v00), cmul(b01,v01));
                c32 w01 = cadd(cmul(b10,v00), cmul(b11,v01));
                c32 w10 = cadd(cmul(b00,v10), cmul(b01,v11));
                c32 w11 = cadd(cmul(b10,v10), cmul(b11,v11));
                // apply Ua across qa-bit
                c32 r00 = cadd(cmul(a00,w00), cmul(a01,w10));
                c32 r10 = cadd(cmul(a10,w00), cmul(a11,w10));
                c32 r01 = cadd(cmul(a00,w01), cmul(a01,w11));
                c32 r11 = cadd(cmul(a10,w01), cmul(a11,w11));
                st[i00] = make_float2(r00.x, r00.y);
                st[i01] = make_float2(r01.x, r01.y);
                st[i10] = make_float2(r10.x, r10.y);
                st[i11] = make_float2(r11.x, r11.y);
            }
            __syncthreads();
        }

        // ---- register pass: qubits 10..13 (idx bits 3..0), 16 contiguous amps/thread ----
        {
            const int t4   = tid & 15;
            const int base = tid << 4;
            c32 v[16];
            #pragma unroll
            for (int j = 0; j < 16; ++j) {   // XOR-swizzled order: 4-way max conflict
                float2 tv = st[base | (j ^ t4)];
                v[j] = {tv.x, tv.y};
            }
            #pragma unroll
            for (int p = 3; p >= 0; --p) {   // qubit q = 13-p
                const float* U = Um[l][13 - p];
                c32 u00={U[0],U[1]}, u01={U[2],U[3]}, u10={U[4],U[5]}, u11={U[6],U[7]};
                // register j holds element with low bits (j ^ t4): role swap if t4 bit p set
                const bool sw = (t4 >> p) & 1;
                c32 m0 = sw ? u11 : u00;
                c32 m1 = sw ? u10 : u01;
                c32 m2 = sw ? u01 : u10;
                c32 m3 = sw ? u00 : u11;
                const int s = 1 << p;
                #pragma unroll
                for (int rr = 0; rr < 16; ++rr) {
                    if (rr & s) continue;
                    c32 A = v[rr], Bv = v[rr | s];
                    v[rr]     = cadd(cmul(m0, A), cmul(m1, Bv));
                    v[rr | s] = cadd(cmul(m2, A), cmul(m3, Bv));
                }
            }
            #pragma unroll
            for (int j = 0; j < 16; ++j) {
                st[base | (j ^ t4)] = make_float2(v[j].x, v[j].y);
            }
        }
        __syncthreads();

        // ---- entangling chain = Gray-code permutation + phase (one gather pass) ----
        {
            c32 tmp[APT];
            #pragma unroll
            for (int j = 0; j < APT; ++j) {
                int y  = tid + j*NT;
                int xs = y ^ (y >> 1);               // inverse prefix-XOR permutation
                float2 v = st[xs];
                float ang = tlo[l][y & 127] + thi[l][(y >> 7) & 63];
                float sn, cs;
                __sincosf(ang, &sn, &cs);
                tmp[j] = { cs*v.x - sn*v.y, cs*v.y + sn*v.x };
            }
            __syncthreads();
            #pragma unroll
            for (int j = 0; j < APT; ++j) {
                st[tid + j*NT] = make_float2(tmp[j].x, tmp[j].y);
            }
        }
        __syncthreads();
    }

    // ---------------- output: <Z_i> = sum over amps of (+/-)|amp|^2 ----------------
    float acc[NQ];
    #pragma unroll
    for (int i = 0; i < NQ; ++i) acc[i] = 0.f;
    #pragma unroll
    for (int j = 0; j < APT; ++j) {
        int idx = tid + j*NT;
        float2 v = st[idx];
        float pr = v.x*v.x + v.y*v.y;
        #pragma unroll
        for (int p = 0; p < NQ; ++p) {       // qubit NQ-1-p at bit position p
            acc[NQ-1-p] += ((idx >> p) & 1) ? -pr : pr;
        }
    }
    #pragma unroll
    for (int off = 32; off >= 1; off >>= 1) {
        #pragma unroll
        for (int i = 0; i < NQ; ++i)
            acc[i] += __shfl_down(acc[i], off, 64);
    }
    const int wid = tid >> 6, lane = tid & 63;
    if (lane == 0) {
        #pragma unroll
        for (int i = 0; i < NQ; ++i) red[wid][i] = acc[i];
    }
    __syncthreads();
    if (tid < NQ) {
        float s = 0.f;
        #pragma unroll
        for (int w = 0; w < NT/64; ++w) s += red[w][tid];
        out[b*NQ + tid] = s;
    }
}

extern "C" void kernel_launch(void* const* d_in, const int* in_sizes, int n_in,
                              void* d_out, int out_size, void* d_ws, size_t ws_size,
                              hipStream_t stream) {
    (void)d_ws; (void)ws_size; (void)n_in; (void)out_size;
    const float* x    = (const float*)d_in[0];
    const float* prx  = (const float*)d_in[1];
    const float* pry  = (const float*)d_in[2];
    const float* prz  = (const float*)d_in[3];
    const float* pent = (const float*)d_in[4];
    float* out = (float*)d_out;
    const int B = in_sizes[0] / NQ;
    qc_kernel<<<B, NT, 0, stream>>>(x, prx, pry, prz, pent, out);
}

// Round 4
// 174.029 us; speedup vs baseline: 1.2333x; 1.2333x over previous
//
#include <hip/hip_runtime.h>
#include <math.h>

#define NQ 14
#define NL 4
#define NS (1 << NQ)      // 16384 amplitudes
#define NT 1024           // threads per block
#define APT (NS / NT)     // 16 amps per thread

struct c32 { float x, y; };
__device__ __forceinline__ c32 cmul(c32 a, c32 b) { return {a.x*b.x - a.y*b.y, a.x*b.y + a.y*b.x}; }
__device__ __forceinline__ c32 cadd(c32 a, c32 b) { return {a.x + b.x, a.y + b.y}; }

// LDS = 137 KB -> 1 block/CU, i.e. exactly 4 waves/EU with 1024 threads.
// Rounds 1/2: compiler budgeted 64 VGPRs (8 waves/EU target) and spilled
// per-thread arrays -> ~185 MB scratch HBM traffic = the entire runtime.
// Two-pronged fix: (a) amdgpu_waves_per_eu(4,4) pins budget at 512/4 = 128
// VGPRs; (b) structural pressure reduction (gather split via Gray-code
// MSB-block-diagonality, layer-3 gather fused into output) so peak live
// set ~55 regs fits even a 64-reg budget.
__global__ __launch_bounds__(NT) __attribute__((amdgpu_waves_per_eu(4, 4)))
void qc_kernel(const float* __restrict__ x,
               const float* __restrict__ prx,
               const float* __restrict__ pry,
               const float* __restrict__ prz,
               const float* __restrict__ pent,
               float* __restrict__ out)
{
    __shared__ float2 st[NS];            // 128 KB state
    __shared__ float  Um[NL][NQ][8];     // fused RZ*RY*RX 2x2 complex per (layer,qubit)
    __shared__ float  tlo[NL][128];      // entangle phase table, bit positions 0..6
    __shared__ float  thi[NL][64];       // bit positions 7..12
    __shared__ float  encc[NQ], encs[NQ];
    __shared__ float  red[NT/64][NQ];

    const int tid = threadIdx.x;
    const int b   = blockIdx.x;

    // ---------------- precompute (one barrier) ----------------
    if (tid < NL*NQ) {
        int l = tid / NQ, q = tid % NQ;
        float hx = 0.5f*prx[l*NQ+q], hy = 0.5f*pry[l*NQ+q], hz = 0.5f*prz[l*NQ+q];
        float cx = cosf(hx), sx = sinf(hx);
        float cy = cosf(hy), sy = sinf(hy);
        float cz = cosf(hz), sz = sinf(hz);
        // M = Ry*Rx
        c32 m00 = { cy*cx,  sy*sx };
        c32 m01 = {-sy*cx, -cy*sx };
        c32 m10 = { sy*cx, -cy*sx };
        c32 m11 = { cy*cx, -sy*sx };
        // U = Rz*M : row0 *= e^{-i hz}, row1 *= e^{+i hz}
        c32 e0 = {cz, -sz}, e1 = {cz, sz};
        c32 u00 = cmul(e0, m00), u01 = cmul(e0, m01);
        c32 u10 = cmul(e1, m10), u11 = cmul(e1, m11);
        float* U = Um[l][q];
        U[0]=u00.x; U[1]=u00.y; U[2]=u01.x; U[3]=u01.y;
        U[4]=u10.x; U[5]=u10.y; U[6]=u11.x; U[7]=u11.y;
    } else if (tid >= 64 && tid < 64 + NL*192) {
        int t2 = tid - 64;
        int l = t2 / 192, r = t2 % 192;
        if (r < 128) {                       // positions p=0..6, theta index 12-p
            float a = 0.f;
            for (int p = 0; p < 7; ++p) {
                float th = 0.5f * pent[l*(NQ-1) + (12 - p)];
                a += ((r >> p) & 1) ? th : -th;
            }
            tlo[l][r] = a;
        } else {                             // positions p=7..12, theta index 5-p'
            int m = r - 128;
            float a = 0.f;
            for (int p = 0; p < 6; ++p) {
                float th = 0.5f * pent[l*(NQ-1) + (5 - p)];
                a += ((m >> p) & 1) ? th : -th;
            }
            thi[l][m] = a;
        }
    } else if (tid >= 960 && tid < 960 + NQ) {
        int i = tid - 960;
        float th = tanhf(x[b*NQ + i]) * 3.14159265358979323846f;
        encc[i] = cosf(0.5f*th);
        encs[i] = sinf(0.5f*th);
    }
    __syncthreads();

    // ---------------- init: product state from RY encoding ----------------
    {
        float prodLow = 1.f;
        #pragma unroll
        for (int p = 0; p < 10; ++p) {       // idx bits 0..9 come from tid; qubit = 13-p
            prodLow *= ((tid >> p) & 1) ? encs[13-p] : encc[13-p];
        }
        #pragma unroll
        for (int j = 0; j < APT; ++j) {      // idx bits 10..13 come from j; qubit = 3..0
            float a = prodLow;
            a *= (j & 1) ? encs[3] : encc[3];
            a *= (j & 2) ? encs[2] : encc[2];
            a *= (j & 4) ? encs[1] : encc[1];
            a *= (j & 8) ? encs[0] : encc[0];
            st[tid + j*NT] = make_float2(a, 0.f);
        }
    }
    __syncthreads();

    #pragma unroll 1
    for (int l = 0; l < NL; ++l) {
        // ---- five fused 2-qubit rotation passes: qubit pairs (0,1)..(8,9) ----
        #pragma unroll
        for (int g = 0; g < 5; ++g) {
            const int qa = 2*g, qb = 2*g + 1;
            const int pb = 13 - qb;          // 12,10,8,6,4
            const float* Ua = Um[l][qa];
            const float* Ub = Um[l][qb];
            c32 a00={Ua[0],Ua[1]}, a01={Ua[2],Ua[3]}, a10={Ua[4],Ua[5]}, a11={Ua[6],Ua[7]};
            c32 b00={Ub[0],Ub[1]}, b01={Ub[2],Ub[3]}, b10={Ub[4],Ub[5]}, b11={Ub[6],Ub[7]};
            const int sb = 1 << pb;
            const int maskLow = sb - 1;
            #pragma unroll
            for (int m = 0; m < 4; ++m) {
                int t = tid + m*NT;          // tuple index in [0,4096)
                int i00 = ((t & ~maskLow) << 2) | (t & maskLow);
                int i01 = i00 | sb;
                int i10 = i00 | (sb << 1);
                int i11 = i01 | (sb << 1);
                float2 f00 = st[i00], f01 = st[i01], f10 = st[i10], f11 = st[i11];
                c32 v00 = {f00.x,f00.y}, v01 = {f01.x,f01.y}, v10 = {f10.x,f10.y}, v11 = {f11.x,f11.y};
                // apply Ub across qb-bit
                c32 w00 = cadd(cmul(b00,v00), cmul(b01,v01));
                c32 w01 = cadd(cmul(b10,v00), cmul(b11,v01));
                c32 w10 = cadd(cmul(b00,v10), cmul(b01,v11));
                c32 w11 = cadd(cmul(b10,v10), cmul(b11,v11));
                // apply Ua across qa-bit
                c32 r00 = cadd(cmul(a00,w00), cmul(a01,w10));
                c32 r10 = cadd(cmul(a10,w00), cmul(a11,w10));
                c32 r01 = cadd(cmul(a00,w01), cmul(a01,w11));
                c32 r11 = cadd(cmul(a10,w01), cmul(a11,w11));
                st[i00] = make_float2(r00.x, r00.y);
                st[i01] = make_float2(r01.x, r01.y);
                st[i10] = make_float2(r10.x, r10.y);
                st[i11] = make_float2(r11.x, r11.y);
            }
            __syncthreads();
        }

        // ---- register pass: qubits 10..13 (idx bits 3..0), 16 contiguous amps/thread ----
        {
            const int t4   = tid & 15;
            const int base = tid << 4;
            c32 v[16];
            #pragma unroll
            for (int j = 0; j < 16; ++j) {   // XOR-swizzled order: 4-way max conflict
                float2 tv = st[base | (j ^ t4)];
                v[j] = {tv.x, tv.y};
            }
            #pragma unroll
            for (int p = 3; p >= 0; --p) {   // qubit q = 13-p
                const float* U = Um[l][13 - p];
                // register j holds element with low bits (j ^ t4): role swap if t4 bit p set
                const bool sw = (t4 >> p) & 1;
                c32 m0 = sw ? c32{U[6],U[7]} : c32{U[0],U[1]};
                c32 m1 = sw ? c32{U[4],U[5]} : c32{U[2],U[3]};
                c32 m2 = sw ? c32{U[2],U[3]} : c32{U[4],U[5]};
                c32 m3 = sw ? c32{U[0],U[1]} : c32{U[6],U[7]};
                const int s = 1 << p;
                #pragma unroll
                for (int rr = 0; rr < 16; ++rr) {
                    if (rr & s) continue;
                    c32 A = v[rr], Bv = v[rr | s];
                    v[rr]     = cadd(cmul(m0, A), cmul(m1, Bv));
                    v[rr | s] = cadd(cmul(m2, A), cmul(m3, Bv));
                }
            }
            #pragma unroll
            for (int j = 0; j < 16; ++j) {
                st[base | (j ^ t4)] = make_float2(v[j].x, v[j].y);
            }
        }
        __syncthreads();

        // ---- entangling chain = Gray-code permutation + phase ----
        // x = y^(y>>1) preserves high bits: y<8192 <=> x<8192, so the
        // permutation is block-diagonal in bit 13 and can run as two
        // half-sweeps with only 8 live c32 each (register-pressure hedge).
        // Layer 3's gather is fused into the output epilogue below.
        if (l != NL-1) {
            c32 tmp[8];
            #pragma unroll 1
            for (int h = 0; h < 2; ++h) {
                #pragma unroll
                for (int j = 0; j < 8; ++j) {
                    int y  = tid + (h*8 + j)*NT;
                    int xs = y ^ (y >> 1);           // inverse prefix-XOR permutation
                    float2 v = st[xs];
                    float ang = tlo[l][y & 127] + thi[l][(y >> 7) & 63];
                    float sn, cs;
                    __sincosf(ang, &sn, &cs);
                    tmp[j] = { cs*v.x - sn*v.y, cs*v.y + sn*v.x };
                }
                __syncthreads();
                #pragma unroll
                for (int j = 0; j < 8; ++j) {
                    st[tid + (h*8 + j)*NT] = make_float2(tmp[j].x, tmp[j].y);
                }
                __syncthreads();
            }
        }
    }

    // ---------------- epilogue: layer-3 gather+phase fused with <Z_i> ----------------
    float acc[NQ];
    #pragma unroll
    for (int i = 0; i < NQ; ++i) acc[i] = 0.f;
    #pragma unroll
    for (int j = 0; j < APT; ++j) {
        int y  = tid + j*NT;
        int xs = y ^ (y >> 1);
        float2 v = st[xs];
        float ang = tlo[NL-1][y & 127] + thi[NL-1][(y >> 7) & 63];
        float sn, cs;
        __sincosf(ang, &sn, &cs);
        float re = cs*v.x - sn*v.y;
        float im = cs*v.y + sn*v.x;
        float pr = re*re + im*im;
        #pragma unroll
        for (int p = 0; p < NQ; ++p) {       // qubit NQ-1-p at bit position p
            acc[NQ-1-p] += ((y >> p) & 1) ? -pr : pr;
        }
    }
    #pragma unroll
    for (int off = 32; off >= 1; off >>= 1) {
        #pragma unroll
        for (int i = 0; i < NQ; ++i)
            acc[i] += __shfl_down(acc[i], off, 64);
    }
    const int wid = tid >> 6, lane = tid & 63;
    if (lane == 0) {
        #pragma unroll
        for (int i = 0; i < NQ; ++i) red[wid][i] = acc[i];
    }
    __syncthreads();
    if (tid < NQ) {
        float s = 0.f;
        #pragma unroll
        for (int w = 0; w < NT/64; ++w) s += red[w][tid];
        out[b*NQ + tid] = s;
    }
}

extern "C" void kernel_launch(void* const* d_in, const int* in_sizes, int n_in,
                              void* d_out, int out_size, void* d_ws, size_t ws_size,
                              hipStream_t stream) {
    (void)d_ws; (void)ws_size; (void)n_in; (void)out_size;
    const float* x    = (const float*)d_in[0];
    const float* prx  = (const float*)d_in[1];
    const float* pry  = (const float*)d_in[2];
    const float* prz  = (const float*)d_in[3];
    const float* pent = (const float*)d_in[4];
    float* out = (float*)d_out;
    const int B = in_sizes[0] / NQ;
    qc_kernel<<<B, NT, 0, stream>>>(x, prx, pry, prz, pent, out);
}

// Round 6
// 141.610 us; speedup vs baseline: 1.5156x; 1.2289x over previous
//
#include <hip/hip_runtime.h>
#include <math.h>

#define NQ 14
#define NL 4
#define NS (1 << NQ)      // 16384 amplitudes
#define NT 1024           // threads per block
#define APT (NS / NT)     // 16 amps per thread

struct c32 { float x, y; };
__device__ __forceinline__ c32 cmul(c32 a, c32 b) { return {a.x*b.x - a.y*b.y, a.x*b.y + a.y*b.x}; }
__device__ __forceinline__ c32 cadd(c32 a, c32 b) { return {a.x + b.x, a.y + b.y}; }

// LDS = 137 KB -> 1 block/CU. Compiler pins a 64-VGPR budget (rounds 1-4:
// occupancy hints ignored), so the kernel is structured to FIT 64 regs:
// the 4-qubit own-amps pass runs as two 2-qubit sub-passes (4 live c32).
// Register position e holds ELEMENT e^t4 (XOR bank-conflict swizzle), so
// each gate acting on bit p needs role-swapped matrices U'[i][j] =
// U[i^sw][j^sw], sw = (t4>>p)&1 — round 5 dropped this and failed; fixed.
__global__ __launch_bounds__(NT) __attribute__((amdgpu_waves_per_eu(4, 4)))
void qc_kernel(const float* __restrict__ x,
               const float* __restrict__ prx,
               const float* __restrict__ pry,
               const float* __restrict__ prz,
               const float* __restrict__ pent,
               float* __restrict__ out)
{
    __shared__ float2 st[NS];            // 128 KB state
    __shared__ float  Um[NL][NQ][8];     // fused RZ*RY*RX 2x2 complex per (layer,qubit)
    __shared__ float  tlo[NL][128];      // entangle phase table, bit positions 0..6
    __shared__ float  thi[NL][64];       // bit positions 7..12
    __shared__ float  encc[NQ], encs[NQ];
    __shared__ float  red[NT/64][NQ];

    const int tid = threadIdx.x;
    const int b   = blockIdx.x;

    // ---------------- precompute (one barrier) ----------------
    if (tid < NL*NQ) {
        int l = tid / NQ, q = tid % NQ;
        float hx = 0.5f*prx[l*NQ+q], hy = 0.5f*pry[l*NQ+q], hz = 0.5f*prz[l*NQ+q];
        float cx = cosf(hx), sx = sinf(hx);
        float cy = cosf(hy), sy = sinf(hy);
        float cz = cosf(hz), sz = sinf(hz);
        // M = Ry*Rx
        c32 m00 = { cy*cx,  sy*sx };
        c32 m01 = {-sy*cx, -cy*sx };
        c32 m10 = { sy*cx, -cy*sx };
        c32 m11 = { cy*cx, -sy*sx };
        // U = Rz*M : row0 *= e^{-i hz}, row1 *= e^{+i hz}
        c32 e0 = {cz, -sz}, e1 = {cz, sz};
        c32 u00 = cmul(e0, m00), u01 = cmul(e0, m01);
        c32 u10 = cmul(e1, m10), u11 = cmul(e1, m11);
        float* U = Um[l][q];
        U[0]=u00.x; U[1]=u00.y; U[2]=u01.x; U[3]=u01.y;
        U[4]=u10.x; U[5]=u10.y; U[6]=u11.x; U[7]=u11.y;
    } else if (tid >= 64 && tid < 64 + NL*192) {
        int t2 = tid - 64;
        int l = t2 / 192, r = t2 % 192;
        if (r < 128) {                       // positions p=0..6, theta index 12-p
            float a = 0.f;
            for (int p = 0; p < 7; ++p) {
                float th = 0.5f * pent[l*(NQ-1) + (12 - p)];
                a += ((r >> p) & 1) ? th : -th;
            }
            tlo[l][r] = a;
        } else {                             // positions p=7..12, theta index 5-p'
            int m = r - 128;
            float a = 0.f;
            for (int p = 0; p < 6; ++p) {
                float th = 0.5f * pent[l*(NQ-1) + (5 - p)];
                a += ((m >> p) & 1) ? th : -th;
            }
            thi[l][m] = a;
        }
    } else if (tid >= 960 && tid < 960 + NQ) {
        int i = tid - 960;
        float th = tanhf(x[b*NQ + i]) * 3.14159265358979323846f;
        encc[i] = cosf(0.5f*th);
        encs[i] = sinf(0.5f*th);
    }
    __syncthreads();

    // ---------------- init: product state from RY encoding ----------------
    {
        float prodLow = 1.f;
        #pragma unroll
        for (int p = 0; p < 10; ++p) {       // idx bits 0..9 come from tid; qubit = 13-p
            prodLow *= ((tid >> p) & 1) ? encs[13-p] : encc[13-p];
        }
        #pragma unroll
        for (int j = 0; j < APT; ++j) {      // idx bits 10..13 come from j; qubit = 3..0
            float a = prodLow;
            a *= (j & 1) ? encs[3] : encc[3];
            a *= (j & 2) ? encs[2] : encc[2];
            a *= (j & 4) ? encs[1] : encc[1];
            a *= (j & 8) ? encs[0] : encc[0];
            st[tid + j*NT] = make_float2(a, 0.f);
        }
    }
    __syncthreads();

    #pragma unroll 1
    for (int l = 0; l < NL; ++l) {
        // ---- five fused 2-qubit rotation passes: qubit pairs (0,1)..(8,9) ----
        #pragma unroll
        for (int g = 0; g < 5; ++g) {
            const int qa = 2*g, qb = 2*g + 1;
            const int pb = 13 - qb;          // 12,10,8,6,4
            const float* Ua = Um[l][qa];
            const float* Ub = Um[l][qb];
            c32 a00={Ua[0],Ua[1]}, a01={Ua[2],Ua[3]}, a10={Ua[4],Ua[5]}, a11={Ua[6],Ua[7]};
            c32 b00={Ub[0],Ub[1]}, b01={Ub[2],Ub[3]}, b10={Ub[4],Ub[5]}, b11={Ub[6],Ub[7]};
            const int sb = 1 << pb;
            const int maskLow = sb - 1;
            #pragma unroll
            for (int m = 0; m < 4; ++m) {
                int t = tid + m*NT;          // tuple index in [0,4096)
                int i00 = ((t & ~maskLow) << 2) | (t & maskLow);
                int i01 = i00 | sb;
                int i10 = i00 | (sb << 1);
                int i11 = i01 | (sb << 1);
                float2 f00 = st[i00], f01 = st[i01], f10 = st[i10], f11 = st[i11];
                c32 v00 = {f00.x,f00.y}, v01 = {f01.x,f01.y}, v10 = {f10.x,f10.y}, v11 = {f11.x,f11.y};
                // apply Ub across qb-bit
                c32 w00 = cadd(cmul(b00,v00), cmul(b01,v01));
                c32 w01 = cadd(cmul(b10,v00), cmul(b11,v01));
                c32 w10 = cadd(cmul(b00,v10), cmul(b01,v11));
                c32 w11 = cadd(cmul(b10,v10), cmul(b11,v11));
                // apply Ua across qa-bit
                c32 r00 = cadd(cmul(a00,w00), cmul(a01,w10));
                c32 r10 = cadd(cmul(a10,w00), cmul(a11,w10));
                c32 r01 = cadd(cmul(a00,w01), cmul(a01,w11));
                c32 r11 = cadd(cmul(a10,w01), cmul(a11,w11));
                st[i00] = make_float2(r00.x, r00.y);
                st[i01] = make_float2(r01.x, r01.y);
                st[i10] = make_float2(r10.x, r10.y);
                st[i11] = make_float2(r11.x, r11.y);
            }
            __syncthreads();
        }

        // ---- low-pressure 4-qubit pass: qubits 10..13 on own 16 amps ----
        // Thread owns amps [tid*16, tid*16+16); position e holds element e^t4.
        // Two 2-qubit sub-passes, 4 live c32 each, no barriers (exclusive
        // ownership). Role-swapped matrices compensate the XOR relabeling.
        {
            const int t4   = tid & 15;
            const int base = tid << 4;

            // sub-pass A: qubit 10 (bit 3, Ua) and qubit 11 (bit 2, Ub)
            {
                const float* Ua = Um[l][10];
                const float* Ub = Um[l][11];
                const int swa = (t4 >> 3) & 1, swb = (t4 >> 2) & 1;
                c32 a00 = swa ? c32{Ua[6],Ua[7]} : c32{Ua[0],Ua[1]};
                c32 a01 = swa ? c32{Ua[4],Ua[5]} : c32{Ua[2],Ua[3]};
                c32 a10 = swa ? c32{Ua[2],Ua[3]} : c32{Ua[4],Ua[5]};
                c32 a11 = swa ? c32{Ua[0],Ua[1]} : c32{Ua[6],Ua[7]};
                c32 b00 = swb ? c32{Ub[6],Ub[7]} : c32{Ub[0],Ub[1]};
                c32 b01 = swb ? c32{Ub[4],Ub[5]} : c32{Ub[2],Ub[3]};
                c32 b10 = swb ? c32{Ub[2],Ub[3]} : c32{Ub[4],Ub[5]};
                c32 b11 = swb ? c32{Ub[0],Ub[1]} : c32{Ub[6],Ub[7]};
                #pragma unroll
                for (int r = 0; r < 4; ++r) {     // position bits 1,0 fixed = r
                    const int p00 = r, p01 = r|4, p10 = r|8, p11 = r|12;
                    float2 f00 = st[base | (p00 ^ t4)];
                    float2 f01 = st[base | (p01 ^ t4)];
                    float2 f10 = st[base | (p10 ^ t4)];
                    float2 f11 = st[base | (p11 ^ t4)];
                    c32 v00={f00.x,f00.y}, v01={f01.x,f01.y}, v10={f10.x,f10.y}, v11={f11.x,f11.y};
                    c32 w00 = cadd(cmul(b00,v00), cmul(b01,v01));
                    c32 w01 = cadd(cmul(b10,v00), cmul(b11,v01));
                    c32 w10 = cadd(cmul(b00,v10), cmul(b01,v11));
                    c32 w11 = cadd(cmul(b10,v10), cmul(b11,v11));
                    c32 r00 = cadd(cmul(a00,w00), cmul(a01,w10));
                    c32 r10 = cadd(cmul(a10,w00), cmul(a11,w10));
                    c32 r01 = cadd(cmul(a00,w01), cmul(a01,w11));
                    c32 r11 = cadd(cmul(a10,w01), cmul(a11,w11));
                    st[base | (p00 ^ t4)] = make_float2(r00.x, r00.y);
                    st[base | (p01 ^ t4)] = make_float2(r01.x, r01.y);
                    st[base | (p10 ^ t4)] = make_float2(r10.x, r10.y);
                    st[base | (p11 ^ t4)] = make_float2(r11.x, r11.y);
                }
            }
            // sub-pass B: qubit 12 (bit 1, Ua) and qubit 13 (bit 0, Ub)
            {
                const float* Ua = Um[l][12];
                const float* Ub = Um[l][13];
                const int swa = (t4 >> 1) & 1, swb = t4 & 1;
                c32 a00 = swa ? c32{Ua[6],Ua[7]} : c32{Ua[0],Ua[1]};
                c32 a01 = swa ? c32{Ua[4],Ua[5]} : c32{Ua[2],Ua[3]};
                c32 a10 = swa ? c32{Ua[2],Ua[3]} : c32{Ua[4],Ua[5]};
                c32 a11 = swa ? c32{Ua[0],Ua[1]} : c32{Ua[6],Ua[7]};
                c32 b00 = swb ? c32{Ub[6],Ub[7]} : c32{Ub[0],Ub[1]};
                c32 b01 = swb ? c32{Ub[4],Ub[5]} : c32{Ub[2],Ub[3]};
                c32 b10 = swb ? c32{Ub[2],Ub[3]} : c32{Ub[4],Ub[5]};
                c32 b11 = swb ? c32{Ub[0],Ub[1]} : c32{Ub[6],Ub[7]};
                #pragma unroll
                for (int r = 0; r < 16; r += 4) { // position bits 3,2 fixed
                    const int p00 = r, p01 = r|1, p10 = r|2, p11 = r|3;
                    float2 f00 = st[base | (p00 ^ t4)];
                    float2 f01 = st[base | (p01 ^ t4)];
                    float2 f10 = st[base | (p10 ^ t4)];
                    float2 f11 = st[base | (p11 ^ t4)];
                    c32 v00={f00.x,f00.y}, v01={f01.x,f01.y}, v10={f10.x,f10.y}, v11={f11.x,f11.y};
                    c32 w00 = cadd(cmul(b00,v00), cmul(b01,v01));
                    c32 w01 = cadd(cmul(b10,v00), cmul(b11,v01));
                    c32 w10 = cadd(cmul(b00,v10), cmul(b01,v11));
                    c32 w11 = cadd(cmul(b10,v10), cmul(b11,v11));
                    c32 r00 = cadd(cmul(a00,w00), cmul(a01,w10));
                    c32 r10 = cadd(cmul(a10,w00), cmul(a11,w10));
                    c32 r01 = cadd(cmul(a00,w01), cmul(a01,w11));
                    c32 r11 = cadd(cmul(a10,w01), cmul(a11,w11));
                    st[base | (p00 ^ t4)] = make_float2(r00.x, r00.y);
                    st[base | (p01 ^ t4)] = make_float2(r01.x, r01.y);
                    st[base | (p10 ^ t4)] = make_float2(r10.x, r10.y);
                    st[base | (p11 ^ t4)] = make_float2(r11.x, r11.y);
                }
            }
        }
        __syncthreads();

        // ---- entangling chain = Gray-code permutation + phase ----
        // x = y^(y>>1) preserves bit 13: two half-sweeps, 8 live c32 each.
        // Layer 3's gather is fused into the output epilogue below.
        if (l != NL-1) {
            c32 tmp[8];
            #pragma unroll 1
            for (int h = 0; h < 2; ++h) {
                #pragma unroll
                for (int j = 0; j < 8; ++j) {
                    int y  = tid + (h*8 + j)*NT;
                    int xs = y ^ (y >> 1);           // inverse prefix-XOR permutation
                    float2 v = st[xs];
                    float ang = tlo[l][y & 127] + thi[l][(y >> 7) & 63];
                    float sn, cs;
                    __sincosf(ang, &sn, &cs);
                    tmp[j] = { cs*v.x - sn*v.y, cs*v.y + sn*v.x };
                }
                __syncthreads();
                #pragma unroll
                for (int j = 0; j < 8; ++j) {
                    st[tid + (h*8 + j)*NT] = make_float2(tmp[j].x, tmp[j].y);
                }
                __syncthreads();
            }
        }
    }

    // ---------------- epilogue: layer-3 gather+phase fused with <Z_i> ----------------
    float acc[NQ];
    #pragma unroll
    for (int i = 0; i < NQ; ++i) acc[i] = 0.f;
    #pragma unroll
    for (int j = 0; j < APT; ++j) {
        int y  = tid + j*NT;
        int xs = y ^ (y >> 1);
        float2 v = st[xs];
        float ang = tlo[NL-1][y & 127] + thi[NL-1][(y >> 7) & 63];
        float sn, cs;
        __sincosf(ang, &sn, &cs);
        float re = cs*v.x - sn*v.y;
        float im = cs*v.y + sn*v.x;
        float pr = re*re + im*im;
        #pragma unroll
        for (int p = 0; p < NQ; ++p) {       // qubit NQ-1-p at bit position p
            acc[NQ-1-p] += ((y >> p) & 1) ? -pr : pr;
        }
    }
    #pragma unroll
    for (int off = 32; off >= 1; off >>= 1) {
        #pragma unroll
        for (int i = 0; i < NQ; ++i)
            acc[i] += __shfl_down(acc[i], off, 64);
    }
    const int wid = tid >> 6, lane = tid & 63;
    if (lane == 0) {
        #pragma unroll
        for (int i = 0; i < NQ; ++i) red[wid][i] = acc[i];
    }
    __syncthreads();
    if (tid < NQ) {
        float s = 0.f;
        #pragma unroll
        for (int w = 0; w < NT/64; ++w) s += red[w][tid];
        out[b*NQ + tid] = s;
    }
}

extern "C" void kernel_launch(void* const* d_in, const int* in_sizes, int n_in,
                              void* d_out, int out_size, void* d_ws, size_t ws_size,
                              hipStream_t stream) {
    (void)d_ws; (void)ws_size; (void)n_in; (void)out_size;
    const float* x    = (const float*)d_in[0];
    const float* prx  = (const float*)d_in[1];
    const float* pry  = (const float*)d_in[2];
    const float* prz  = (const float*)d_in[3];
    const float* pent = (const float*)d_in[4];
    float* out = (float*)d_out;
    const int B = in_sizes[0] / NQ;
    qc_kernel<<<B, NT, 0, stream>>>(x, prx, pry, prz, pent, out);
}